// Round 1
// baseline (67.297 us; speedup 1.0000x reference)
//
#include <hip/hip_runtime.h>
#include <math.h>

// Problem constants (from reference setup_inputs)
#define BSZ   16     // batch
#define NCAPS 1152   // num primary caps
#define DP    8      // dim primary caps
#define MCAPS 10     // num digit caps
#define DD    16     // dim digit caps

#define NC     24               // n-chunk handled per block
#define NCHUNK (NCAPS / NC)     // 48 chunks per m

// ---------------------------------------------------------------------------
// Kernel 1: S[b,m,d] += sum_{n in chunk} (1 + Bp[m,n]) * <W[m,n,d,:], u[b,n,:]>
// One block per (m, n-chunk). 256 threads = (b in 0..15) x (d in 0..15).
// ---------------------------------------------------------------------------
__global__ __launch_bounds__(256) void digitcaps_partial(
    const float* __restrict__ u,   // [BSZ][NCAPS][DP]
    const float* __restrict__ W,   // [MCAPS][NCAPS][DD][DP]
    const float* __restrict__ Bp,  // [MCAPS][NCAPS]  (B_prior squeezed)
    float* __restrict__ S)         // [BSZ][MCAPS][DD] accumulators (pre-zeroed)
{
    __shared__ float w_t[NC][DD][DP];    // 3072 floats = 12 KB
    __shared__ float u_t[BSZ][NC][DP];   // 3072 floats = 12 KB
    __shared__ float bp_t[NC];

    const int t  = threadIdx.x;
    const int m  = blockIdx.x / NCHUNK;
    const int n0 = (blockIdx.x % NCHUNK) * NC;

    // --- stage W tile: NC*DD*DP = 3072 contiguous floats = 768 float4 ---
    const float4* wg = (const float4*)(W + ((size_t)(m * NCAPS + n0)) * DD * DP);
    float4* wl = (float4*)&w_t[0][0][0];
#pragma unroll
    for (int i = 0; i < 3; ++i) {
        wl[t + 256 * i] = wg[t + 256 * i];
    }

    // --- stage u tile: for each b, NC*DP = 192 contiguous floats (48 float4) ---
    float4* ul = (float4*)&u_t[0][0][0];
#pragma unroll
    for (int i = 0; i < 3; ++i) {
        int idx = t + 256 * i;               // 0..767
        int b   = idx / (NC * DP / 4);       // /48
        int off = idx % (NC * DP / 4);
        ul[idx] = ((const float4*)(u + ((size_t)(b * NCAPS + n0)) * DP))[off];
    }

    if (t < NC) bp_t[t] = 1.0f + Bp[m * NCAPS + n0 + t];
    __syncthreads();

    const int b = t >> 4;   // 0..15
    const int d = t & 15;   // 0..15

    float acc = 0.0f;
#pragma unroll
    for (int n = 0; n < NC; ++n) {
        const float4 w0 = *(const float4*)&w_t[n][d][0];
        const float4 w1 = *(const float4*)&w_t[n][d][4];
        const float4 u0 = *(const float4*)&u_t[b][n][0];
        const float4 u1 = *(const float4*)&u_t[b][n][4];
        float dot = w0.x * u0.x + w0.y * u0.y + w0.z * u0.z + w0.w * u0.w
                  + w1.x * u1.x + w1.y * u1.y + w1.z * u1.z + w1.w * u1.w;
        acc += bp_t[n] * dot;
    }

    atomicAdd(&S[((size_t)b * MCAPS + m) * DD + d], acc);
}

// ---------------------------------------------------------------------------
// Kernel 2: out[b,m,:] = squash(S[b,m,:])
//   norm  = ||S||_2 over d
//   coef  = 1 - exp(-norm)
//   out   = coef * S / (norm + 1e-7)
// One block; thread t < 160 owns one (b,m) pair (flat index matches S layout).
// ---------------------------------------------------------------------------
__global__ __launch_bounds__(256) void digitcaps_squash(
    const float* __restrict__ S,   // [BSZ*MCAPS][DD]
    float* __restrict__ out)       // [BSZ*MCAPS][DD]
{
    const int t = threadIdx.x;
    if (t >= BSZ * MCAPS) return;

    const float* s = S + (size_t)t * DD;
    float v[DD];
    float ss = 0.0f;
#pragma unroll
    for (int d = 0; d < DD; ++d) {
        v[d] = s[d];
        ss += v[d] * v[d];
    }
    float norm  = sqrtf(ss);
    float coef  = 1.0f - expf(-norm);
    float scale = coef / (norm + 1e-7f);
#pragma unroll
    for (int d = 0; d < DD; ++d) {
        out[(size_t)t * DD + d] = scale * v[d];
    }
}

extern "C" void kernel_launch(void* const* d_in, const int* in_sizes, int n_in,
                              void* d_out, int out_size, void* d_ws, size_t ws_size,
                              hipStream_t stream) {
    const float* u  = (const float*)d_in[0];  // primary_caps [16,1152,8]
    const float* W  = (const float*)d_in[1];  // W            [10,1152,16,8]
    const float* Bp = (const float*)d_in[2];  // B_prior      [10,1,1152]
    float* out = (float*)d_out;               // [16,10,16]
    float* S   = (float*)d_ws;                // 2560-float accumulator

    // Workspace is re-poisoned to 0xAA before every timed launch — zero it.
    hipMemsetAsync(S, 0, (size_t)BSZ * MCAPS * DD * sizeof(float), stream);

    digitcaps_partial<<<dim3(MCAPS * NCHUNK), dim3(256), 0, stream>>>(u, W, Bp, S);
    digitcaps_squash<<<dim3(1), dim3(256), 0, stream>>>(S, out);
}

// Round 2
// 66.599 us; speedup vs baseline: 1.0105x; 1.0105x over previous
//
#include <hip/hip_runtime.h>
#include <math.h>

// Problem constants (from reference setup_inputs)
#define BSZ   16     // batch
#define NCAPS 1152   // num primary caps
#define DP    8      // dim primary caps
#define MCAPS 10     // num digit caps
#define DD    16     // dim digit caps

#define NC     24               // n-chunk handled per block
#define NCHUNK (NCAPS / NC)     // 48 chunks per m

// ---------------------------------------------------------------------------
// Kernel 1: part[m][chunk][b][d] = sum_{n in chunk} (1+Bp[m,n]) * <W[m,n,d,:], u[b,n,:]>
// One block per (m, n-chunk). 256 threads = (b in 0..15) x (d in 0..15).
// Atomic-free: each block writes its own 256-float partial tile (coalesced).
// ---------------------------------------------------------------------------
__global__ __launch_bounds__(256) void digitcaps_partial(
    const float* __restrict__ u,    // [BSZ][NCAPS][DP]
    const float* __restrict__ W,    // [MCAPS][NCAPS][DD][DP]
    const float* __restrict__ Bp,   // [MCAPS][NCAPS]  (B_prior squeezed)
    float* __restrict__ part)       // [MCAPS][NCHUNK][BSZ][DD]
{
    __shared__ float w_t[NC][DD][DP];    // 3072 floats = 12 KB
    __shared__ float u_t[BSZ][NC][DP];   // 3072 floats = 12 KB
    __shared__ float bp_t[NC];

    const int t  = threadIdx.x;
    const int m  = blockIdx.x / NCHUNK;
    const int n0 = (blockIdx.x % NCHUNK) * NC;

    // --- stage W tile: NC*DD*DP = 3072 contiguous floats = 768 float4 ---
    const float4* wg = (const float4*)(W + ((size_t)(m * NCAPS + n0)) * DD * DP);
    float4* wl = (float4*)&w_t[0][0][0];
#pragma unroll
    for (int i = 0; i < 3; ++i) {
        wl[t + 256 * i] = wg[t + 256 * i];
    }

    // --- stage u tile: for each b, NC*DP = 192 contiguous floats (48 float4) ---
    float4* ul = (float4*)&u_t[0][0][0];
#pragma unroll
    for (int i = 0; i < 3; ++i) {
        int idx = t + 256 * i;               // 0..767
        int b   = idx / (NC * DP / 4);       // /48
        int off = idx % (NC * DP / 4);
        ul[idx] = ((const float4*)(u + ((size_t)(b * NCAPS + n0)) * DP))[off];
    }

    if (t < NC) bp_t[t] = 1.0f + Bp[m * NCAPS + n0 + t];
    __syncthreads();

    const int b = t >> 4;   // 0..15
    const int d = t & 15;   // 0..15

    float acc = 0.0f;
#pragma unroll
    for (int n = 0; n < NC; ++n) {
        const float4 w0 = *(const float4*)&w_t[n][d][0];
        const float4 w1 = *(const float4*)&w_t[n][d][4];
        const float4 u0 = *(const float4*)&u_t[b][n][0];
        const float4 u1 = *(const float4*)&u_t[b][n][4];
        float dot = w0.x * u0.x + w0.y * u0.y + w0.z * u0.z + w0.w * u0.w
                  + w1.x * u1.x + w1.y * u1.y + w1.z * u1.z + w1.w * u1.w;
        acc += bp_t[n] * dot;
    }

    // One coalesced store per thread; layout matches blockIdx*256 + t.
    part[(size_t)blockIdx.x * 256 + t] = acc;
}

// ---------------------------------------------------------------------------
// Kernel 2: out[b,m,d] = squash(sum_chunk part[m][chunk][b][d])
// 10 blocks x 256 threads: global thread g owns output element g, where
// g = (b*MCAPS + m)*DD + d. The 16 threads sharing (b,m) are contiguous
// lanes -> 16-wide __shfl_xor butterfly for the squared norm.
// ---------------------------------------------------------------------------
__global__ __launch_bounds__(256) void digitcaps_reduce_squash(
    const float* __restrict__ part, // [MCAPS][NCHUNK][BSZ][DD]
    float* __restrict__ out)        // [BSZ][MCAPS][DD]
{
    const int g  = blockIdx.x * 256 + threadIdx.x;  // 0..2559
    const int d  = g & 15;
    const int bm = g >> 4;          // b*MCAPS + m
    const int m  = bm % MCAPS;
    const int b  = bm / MCAPS;

    float s = 0.0f;
#pragma unroll
    for (int c = 0; c < NCHUNK; ++c) {
        s += part[(((size_t)(m * NCHUNK + c) * BSZ + b) << 4) + d];
    }

    // squared-norm reduction across the 16 lanes sharing (b,m)
    float ss = s * s;
#pragma unroll
    for (int w = 1; w < 16; w <<= 1) {
        ss += __shfl_xor(ss, w, 16);
    }

    float norm  = sqrtf(ss);
    float scale = (1.0f - expf(-norm)) / (norm + 1e-7f);
    out[g] = scale * s;
}

extern "C" void kernel_launch(void* const* d_in, const int* in_sizes, int n_in,
                              void* d_out, int out_size, void* d_ws, size_t ws_size,
                              hipStream_t stream) {
    const float* u  = (const float*)d_in[0];  // primary_caps [16,1152,8]
    const float* W  = (const float*)d_in[1];  // W            [10,1152,16,8]
    const float* Bp = (const float*)d_in[2];  // B_prior      [10,1,1152]
    float* out  = (float*)d_out;              // [16,10,16]
    float* part = (float*)d_ws;               // 480*256 floats = 491 KB

    digitcaps_partial<<<dim3(MCAPS * NCHUNK), dim3(256), 0, stream>>>(u, W, Bp, part);
    digitcaps_reduce_squash<<<dim3(MCAPS), dim3(256), 0, stream>>>(part, out);
}